// Round 15
// baseline (192.867 us; speedup 1.0000x reference)
//
#include <hip/hip_runtime.h>
#include <hip/hip_fp16.h>
#include <math.h>

#define N_NODES 100000
#define N_EDGES 1600000
#define N_FEATS 128
#define HIDDEN 20
#define N_GRAPHS 256

#define TILE 256
#define NB ((N_NODES + TILE - 1) / TILE)       // 391 dst tiles
#define NQ 4                                   // src quarters
#define QDIV 25000                             // nodes per src quarter
#define NB4 (NB * NQ)                          // 1564 buckets
#define SLOTS4 1280                            // mean 1023 + 8 sigma
#define YSTRIDE 32                             // fp16 row padded to 64 B line

// Static device scratch (fully rewritten each call before any read).
// __device__ symbols resolved in DEVICE code only; host passes selectors.
__device__ __half g_yh[2][(size_t)N_NODES * YSTRIDE];   // fp16 tables, 2 x 6.4 MB
__device__ __half g_p16[NQ][(size_t)N_NODES * YSTRIDE]; // partial sums, 25.6 MB
__device__ float  g_facc[(size_t)N_NODES * HIDDEN];     // final acc f32, 8 MB
__device__ int    g_part[(size_t)NB4 * SLOTS4];         // packed (src<<8)|dl, 8 MB
__device__ int    g_cursor[NB4];
__device__ int    g_rowbeg[NB4 * TILE];                 // 1.6 MB
__device__ int    g_rowend[NB4 * TILE];                 // 1.6 MB
__device__ int    g_col[(size_t)NB4 * SLOTS4];          // bucket-padded CSR, 8 MB

// ---- inline index-dtype detection (int64 edge_index has zero odd words) -----
__device__ __forceinline__ int detect_is64(const int* __restrict__ e32) {
    int acc = 0;
    #pragma unroll
    for (int j = 0; j < 8; j++) {
        int k = j * (N_EDGES / 8) + 997 * j + 13;
        acc |= e32[2 * k + 1];
    }
    return acc == 0;
}

__device__ __forceinline__ void load_edge(const void* eidx, int is64, int e,
                                          int& s, int& d) {
    if (is64) {
        const long long* e64 = (const long long*)eidx;
        s = (int)e64[e];
        d = (int)e64[N_EDGES + e];
    } else {
        const int* e32 = (const int*)eidx;
        s = e32[e];
        d = e32[N_EDGES + e];
    }
}

__global__ __launch_bounds__(512) void zero_kernel() {
    const int i = blockIdx.x * 512 + threadIdx.x;
    if (i < NB4) g_cursor[i] = 0;
}

// ------- partition: edges -> (dst-tile, src-quarter) buckets ------------------
__global__ __launch_bounds__(512) void part_kernel(const void* __restrict__ eidx) {
    __shared__ int hist[NB4];
    __shared__ int base[NB4];
    const int t = threadIdx.x;
    const int e0 = blockIdx.x * 4096;
    for (int i = t; i < NB4; i += 512) hist[i] = 0;
    const int is64 = detect_is64((const int*)eidx);
    __syncthreads();

    int sc[8], dc[8];
    #pragma unroll
    for (int k = 0; k < 8; k++) {
        const int e = e0 + k * 512 + t;
        sc[k] = -1; dc[k] = 0;
        if (e < N_EDGES) {
            int s, d;
            load_edge(eidx, is64, e, s, d);
            if ((unsigned)s < N_NODES && (unsigned)d < N_NODES) {
                sc[k] = s; dc[k] = d;
                atomicAdd(&hist[(d >> 8) * NQ + s / QDIV], 1);
            }
        }
    }
    __syncthreads();
    for (int b = t; b < NB4; b += 512) {
        const int c = hist[b];
        base[b] = c ? atomicAdd(&g_cursor[b], c) : 0;
        hist[b] = 0;   // reuse as local rank counter
    }
    __syncthreads();
    #pragma unroll
    for (int k = 0; k < 8; k++) {
        if (sc[k] >= 0) {
            const int b = (dc[k] >> 8) * NQ + sc[k] / QDIV;
            const int r = atomicAdd(&hist[b], 1);
            const int pos = base[b] + r;
            if (pos < SLOTS4)
                g_part[(size_t)b * SLOTS4 + pos] = (sc[k] << 8) | (dc[k] & 255);
        }
    }
}

// -------- per-bucket LDS counting sort -> padded CSR (rowbeg/rowend/col) -----
__global__ __launch_bounds__(512) void bucketsort_kernel() {
    __shared__ int hist[TILE];
    __shared__ int pfx[TILE];
    __shared__ int cur[TILE];
    __shared__ int sorted[SLOTS4];
    const int t = threadIdx.x;
    const int b = blockIdx.x;
    const int cnt = min(g_cursor[b], SLOTS4);
    const int base = b * SLOTS4;               // padded layout, no scan needed
    if (t < TILE) hist[t] = 0;
    __syncthreads();
    const int* __restrict__ part = g_part + (size_t)b * SLOTS4;
    for (int i = t; i < cnt; i += 512) atomicAdd(&hist[part[i] & 255], 1);
    __syncthreads();
    if (t < TILE) pfx[t] = hist[t];
    __syncthreads();
    for (int off = 1; off < TILE; off <<= 1) {
        int u = (t < TILE && t >= off) ? pfx[t - off] : 0;
        __syncthreads();
        if (t < TILE) pfx[t] += u;
        __syncthreads();
    }
    if (t < TILE) {
        const int ex = pfx[t] - hist[t];   // exclusive prefix
        cur[t] = ex;
        g_rowbeg[b * TILE + t] = base + ex;
        g_rowend[b * TILE + t] = base + ex + hist[t];
    }
    __syncthreads();
    for (int i = t; i < cnt; i += 512) {
        const int rec = part[i];
        const int r = atomicAdd(&cur[rec & 255], 1);
        sorted[r] = rec >> 8;
    }
    __syncthreads();
    for (int i = t; i < cnt; i += 512) g_col[base + i] = sorted[i];
}

// ---------------- mm1: g_yh[0] = fp16(x @ W1) --------------------------------
// 4 threads per row, W k-interleaved in LDS (10 KB). Butterfly shfl combine.
__global__ __launch_bounds__(256) void mm1_kernel(const float* __restrict__ x,
                                                  const float* __restrict__ W) {  // 128x20
    __shared__ float ldsWp[N_FEATS * HIDDEN];   // permuted: [(jl*4+q)*20+c]
    const int t = threadIdx.x;
    for (int i = t; i < N_FEATS * HIDDEN; i += 256) {
        const int korig = i / HIDDEN;
        const int c = i - korig * HIDDEN;
        const int jl = korig & 31;
        const int q = korig >> 5;
        ldsWp[(jl * 4 + q) * HIDDEN + c] = W[i];
    }
    __syncthreads();
    const int r = t >> 2;
    const int q = t & 3;
    const int row = blockIdx.x * 64 + r;
    const bool valid = row < N_NODES;

    float4 v[8];
    if (valid) {
        const float4* rp = (const float4*)&x[(size_t)row * N_FEATS + q * 32];
        #pragma unroll
        for (int i = 0; i < 8; i++) v[i] = rp[i];
    }
    float4 a0 = {0,0,0,0}, a1 = {0,0,0,0}, a2 = {0,0,0,0}, a3 = {0,0,0,0}, a4 = {0,0,0,0};
    if (valid) {
        #pragma unroll
        for (int i = 0; i < 8; i++) {
            const float xv[4] = {v[i].x, v[i].y, v[i].z, v[i].w};
            #pragma unroll
            for (int jj = 0; jj < 4; jj++) {
                const int jl = i * 4 + jj;
                const float4* wp = (const float4*)&ldsWp[(jl * 4 + q) * HIDDEN];
                const float xs = xv[jj];
                float4 w0 = wp[0], w1 = wp[1], w2 = wp[2], w3 = wp[3], w4 = wp[4];
                a0.x = fmaf(xs, w0.x, a0.x); a0.y = fmaf(xs, w0.y, a0.y);
                a0.z = fmaf(xs, w0.z, a0.z); a0.w = fmaf(xs, w0.w, a0.w);
                a1.x = fmaf(xs, w1.x, a1.x); a1.y = fmaf(xs, w1.y, a1.y);
                a1.z = fmaf(xs, w1.z, a1.z); a1.w = fmaf(xs, w1.w, a1.w);
                a2.x = fmaf(xs, w2.x, a2.x); a2.y = fmaf(xs, w2.y, a2.y);
                a2.z = fmaf(xs, w2.z, a2.z); a2.w = fmaf(xs, w2.w, a2.w);
                a3.x = fmaf(xs, w3.x, a3.x); a3.y = fmaf(xs, w3.y, a3.y);
                a3.z = fmaf(xs, w3.z, a3.z); a3.w = fmaf(xs, w3.w, a3.w);
                a4.x = fmaf(xs, w4.x, a4.x); a4.y = fmaf(xs, w4.y, a4.y);
                a4.z = fmaf(xs, w4.z, a4.z); a4.w = fmaf(xs, w4.w, a4.w);
            }
        }
    }
    float acc[20] = {a0.x, a0.y, a0.z, a0.w, a1.x, a1.y, a1.z, a1.w,
                     a2.x, a2.y, a2.z, a2.w, a3.x, a3.y, a3.z, a3.w,
                     a4.x, a4.y, a4.z, a4.w};
    #pragma unroll
    for (int off = 1; off <= 2; off <<= 1) {
        #pragma unroll
        for (int c = 0; c < 20; c++) acc[c] += __shfl_xor(acc[c], off);
    }
    if (valid) {
        __half* yp = &g_yh[0][(size_t)row * YSTRIDE];
        if (q == 0) {
            __half2 h0 = __float22half2_rn(make_float2(acc[0], acc[1]));
            __half2 h1 = __float22half2_rn(make_float2(acc[2], acc[3]));
            __half2 h2 = __float22half2_rn(make_float2(acc[4], acc[5]));
            __half2 h3 = __float22half2_rn(make_float2(acc[6], acc[7]));
            uint4 u; u.x = *(unsigned*)&h0; u.y = *(unsigned*)&h1;
            u.z = *(unsigned*)&h2; u.w = *(unsigned*)&h3;
            *(uint4*)&yp[0] = u;
        } else if (q == 1) {
            __half2 h0 = __float22half2_rn(make_float2(acc[8], acc[9]));
            __half2 h1 = __float22half2_rn(make_float2(acc[10], acc[11]));
            __half2 h2 = __float22half2_rn(make_float2(acc[12], acc[13]));
            __half2 h3 = __float22half2_rn(make_float2(acc[14], acc[15]));
            uint4 u; u.x = *(unsigned*)&h0; u.y = *(unsigned*)&h1;
            u.z = *(unsigned*)&h2; u.w = *(unsigned*)&h3;
            *(uint4*)&yp[8] = u;
        } else if (q == 2) {
            __half2 h0 = __float22half2_rn(make_float2(acc[16], acc[17]));
            __half2 h1 = __float22half2_rn(make_float2(acc[18], acc[19]));
            uint2 u; u.x = *(unsigned*)&h0; u.y = *(unsigned*)&h1;
            *(uint2*)&yp[16] = u;
        }
    }
}

// ------- gtA: per (dst-tile, src-quarter) partial gather ---------------------
// blockIdx: tile = b>>2, quarter j = b&3. With round-robin block->XCD (%8),
// each XCD only touches src-quarter (xcd%4): 1.6 MB, L2-resident.
// No LDS, no atomics; writes fp16 partials to g_p16[j].
__global__ __launch_bounds__(320) void gtA_kernel(int src) {
    const __half* __restrict__ y = g_yh[src];
    const int b = blockIdx.x;
    const int tile = b >> 2;
    const int j = b & 3;
    const int t = threadIdx.x;
    const int nlb = t / 5;
    const int chunk = t - nlb * 5;
    const int cb = chunk * 4;
    #pragma unroll
    for (int it = 0; it < 4; it++) {
        const int dl = it * 64 + nlb;
        const int node = tile * TILE + dl;
        if (node >= N_NODES) break;
        const int idx = b * TILE + dl;
        const int beg = g_rowbeg[idx];
        const int end = g_rowend[idx];
        float sx = 0.f, sy = 0.f, sz = 0.f, sw = 0.f;
        int i = beg;
        for (; i + 4 <= end; i += 4) {
            const int s0 = g_col[i + 0];
            const int s1 = g_col[i + 1];
            const int s2 = g_col[i + 2];
            const int s3 = g_col[i + 3];
            const uint2 u0 = *(const uint2*)&y[(size_t)s0 * YSTRIDE + cb];
            const uint2 u1 = *(const uint2*)&y[(size_t)s1 * YSTRIDE + cb];
            const uint2 u2 = *(const uint2*)&y[(size_t)s2 * YSTRIDE + cb];
            const uint2 u3 = *(const uint2*)&y[(size_t)s3 * YSTRIDE + cb];
            float2 a, c;
            a = __half22float2(*(const __half2*)&u0.x); c = __half22float2(*(const __half2*)&u0.y);
            sx += a.x; sy += a.y; sz += c.x; sw += c.y;
            a = __half22float2(*(const __half2*)&u1.x); c = __half22float2(*(const __half2*)&u1.y);
            sx += a.x; sy += a.y; sz += c.x; sw += c.y;
            a = __half22float2(*(const __half2*)&u2.x); c = __half22float2(*(const __half2*)&u2.y);
            sx += a.x; sy += a.y; sz += c.x; sw += c.y;
            a = __half22float2(*(const __half2*)&u3.x); c = __half22float2(*(const __half2*)&u3.y);
            sx += a.x; sy += a.y; sz += c.x; sw += c.y;
        }
        for (; i < end; i++) {
            const int s = g_col[i];
            const uint2 u = *(const uint2*)&y[(size_t)s * YSTRIDE + cb];
            const float2 f0 = __half22float2(*(const __half2*)&u.x);
            const float2 f1 = __half22float2(*(const __half2*)&u.y);
            sx += f0.x; sy += f0.y; sz += f1.x; sw += f1.y;
        }
        __half2 o0 = __float22half2_rn(make_float2(sx, sy));
        __half2 o1 = __float22half2_rn(make_float2(sz, sw));
        uint2 u; u.x = *(unsigned*)&o0; u.y = *(unsigned*)&o1;
        *(uint2*)&g_p16[j][(size_t)node * YSTRIDE + cb] = u;
    }
}

// ------- gtB: reduce partials + self, then transform -------------------------
template<bool FINAL>
__global__ __launch_bounds__(320) void gtB_kernel(const float* __restrict__ bias,
                                                  const float* __restrict__ W,  // 20x20
                                                  int src) {
    const __half* __restrict__ y = g_yh[src];
    __shared__ float hrow[64][HIDDEN + 1];
    __shared__ float ldsW[HIDDEN * HIDDEN];
    __shared__ float ldsB[HIDDEN];
    const int t = threadIdx.x;
    if (!FINAL) {
        for (int i = t; i < HIDDEN * HIDDEN; i += 320) ldsW[i] = W[i];
        if (t < HIDDEN) ldsB[t] = bias[t];
    }
    const int nl = t / 5;
    const int chunk = t - nl * 5;
    const int cb = chunk * 4;
    const int node = blockIdx.x * 64 + nl;
    float sx = 0.f, sy = 0.f, sz = 0.f, sw = 0.f;
    if (node < N_NODES) {
        const size_t off = (size_t)node * YSTRIDE + cb;
        // self + 4 quarter partials (all coalesced streaming reads)
        uint2 u = *(const uint2*)&y[off];
        float2 f0 = __half22float2(*(const __half2*)&u.x);
        float2 f1 = __half22float2(*(const __half2*)&u.y);
        sx = f0.x; sy = f0.y; sz = f1.x; sw = f1.y;
        #pragma unroll
        for (int j = 0; j < NQ; j++) {
            const uint2 p = *(const uint2*)&g_p16[j][off];
            f0 = __half22float2(*(const __half2*)&p.x);
            f1 = __half22float2(*(const __half2*)&p.y);
            sx += f0.x; sy += f0.y; sz += f1.x; sw += f1.y;
        }
    }
    if (FINAL) {
        if (node < N_NODES) {
            float4 o; o.x = sx; o.y = sy; o.z = sz; o.w = sw;
            *(float4*)&g_facc[(size_t)node * HIDDEN + cb] = o;
        }
        return;
    }
    if (node < N_NODES) {
        hrow[nl][cb + 0] = sx;
        hrow[nl][cb + 1] = sy;
        hrow[nl][cb + 2] = sz;
        hrow[nl][cb + 3] = sw;
    }
    __syncthreads();
    if (node < N_NODES) {
        float h[HIDDEN];
        #pragma unroll
        for (int c = 0; c < HIDDEN; c++) {
            float v = hrow[nl][c] + ldsB[c];
            h[c] = v > 0.f ? v : 0.f;
        }
        float s0 = 0.f, s1 = 0.f, s2 = 0.f, s3 = 0.f;
        #pragma unroll
        for (int k = 0; k < HIDDEN; k++) {
            const float* w = &ldsW[k * HIDDEN + cb];
            s0 = fmaf(h[k], w[0], s0);
            s1 = fmaf(h[k], w[1], s1);
            s2 = fmaf(h[k], w[2], s2);
            s3 = fmaf(h[k], w[3], s3);
        }
        __half2 o0 = __float22half2_rn(make_float2(s0, s1));
        __half2 o1 = __float22half2_rn(make_float2(s2, s3));
        uint2 u;
        u.x = *(unsigned*)&o0;
        u.y = *(unsigned*)&o1;
        *(uint2*)&g_yh[src ^ 1][(size_t)node * YSTRIDE + cb] = u;
    }
}

// ---------------- pool + final linear ----------------------------------------
__global__ __launch_bounds__(256) void pool_kernel(const float* __restrict__ b3,
                                                   const void* __restrict__ batch,
                                                   const void* __restrict__ eidx,
                                                   const float* __restrict__ Wl,  // 40x2
                                                   const float* __restrict__ bl,  // 2
                                                   float* __restrict__ out) {
    const float* __restrict__ acc3 = g_facc;
    const int g = blockIdx.x;
    const int t = threadIdx.x;
    const int is64 = detect_is64((const int*)eidx);
    const int* b32 = (const int*)batch;
    const long long* b64 = (const long long*)batch;
    #define BAT(i) (is64 ? (int)b64[i] : b32[i])
    int lo = 0, hi = N_NODES;
    while (lo < hi) { int mid = (lo + hi) >> 1; if (BAT(mid) < g) lo = mid + 1; else hi = mid; }
    const int start = lo;
    lo = start; hi = N_NODES;
    while (lo < hi) { int mid = (lo + hi) >> 1; if (BAT(mid) < g + 1) lo = mid + 1; else hi = mid; }
    const int end = lo;
    #undef BAT

    float b3r[HIDDEN];
    #pragma unroll
    for (int c = 0; c < HIDDEN; c++) b3r[c] = b3[c];
    float mx[HIDDEN], sm[HIDDEN];
    #pragma unroll
    for (int c = 0; c < HIDDEN; c++) { mx[c] = 0.f; sm[c] = 0.f; }  // relu >= 0

    for (int i = start + t; i < end; i += 256) {
        const float4* rp = (const float4*)&acc3[(size_t)i * HIDDEN];
        float4 q[5] = {rp[0], rp[1], rp[2], rp[3], rp[4]};
        const float* r = (const float*)q;
        #pragma unroll
        for (int c = 0; c < HIDDEN; c++) {
            float v = r[c] + b3r[c];
            v = v > 0.f ? v : 0.f;
            mx[c] = fmaxf(mx[c], v);
            sm[c] += v;
        }
    }
    #pragma unroll
    for (int off = 32; off >= 1; off >>= 1) {
        #pragma unroll
        for (int c = 0; c < HIDDEN; c++) {
            mx[c] = fmaxf(mx[c], __shfl_xor(mx[c], off));
            sm[c] += __shfl_xor(sm[c], off);
        }
    }
    __shared__ float smx[4][HIDDEN];
    __shared__ float ssm[4][HIDDEN];
    const int wave = t >> 6, lane = t & 63;
    if (lane == 0) {
        #pragma unroll
        for (int c = 0; c < HIDDEN; c++) { smx[wave][c] = mx[c]; ssm[wave][c] = sm[c]; }
    }
    __syncthreads();
    if (t == 0) {
        float cnt = (float)(end - start);
        float pooled[2 * HIDDEN];
        #pragma unroll
        for (int c = 0; c < HIDDEN; c++) {
            float m = smx[0][c], s = ssm[0][c];
            #pragma unroll
            for (int w = 1; w < 4; w++) { m = fmaxf(m, smx[w][c]); s += ssm[w][c]; }
            pooled[c] = m;
            pooled[HIDDEN + c] = s / fmaxf(cnt, 1.f);
        }
        #pragma unroll
        for (int c = 0; c < 2; c++) {
            float o = bl[c];
            #pragma unroll
            for (int k = 0; k < 2 * HIDDEN; k++) o = fmaf(pooled[k], Wl[k * 2 + c], o);
            out[g * 2 + c] = o;
        }
    }
}

extern "C" void kernel_launch(void* const* d_in, const int* in_sizes, int n_in,
                              void* d_out, int out_size, void* d_ws, size_t ws_size,
                              hipStream_t stream) {
    const float* x    = (const float*)d_in[0];
    const void* eidx  = d_in[1];
    const void* batch = d_in[2];
    const float* W1  = (const float*)d_in[3];
    const float* b1  = (const float*)d_in[4];
    const float* W2  = (const float*)d_in[5];
    const float* b2  = (const float*)d_in[6];
    const float* W3  = (const float*)d_in[7];
    const float* b3  = (const float*)d_in[8];
    const float* Wl  = (const float*)d_in[9];
    const float* bl  = (const float*)d_in[10];
    float* out = (float*)d_out;
    (void)d_ws; (void)ws_size;

    const int mm1_blocks = (N_NODES + 63) / 64;   // 1563
    const int gtB_blocks = (N_NODES + 63) / 64;   // 1563

    // CSR build: (dst-tile, src-quarter) buckets + LDS counting sort
    zero_kernel<<<4, 512, 0, stream>>>();
    part_kernel<<<NB, 512, 0, stream>>>(eidx);
    bucketsort_kernel<<<NB4, 512, 0, stream>>>();

    // layer 1: yh0 = fp16(x@W1)
    mm1_kernel<<<mm1_blocks, 256, 0, stream>>>(x, W1);
    // layer 2
    gtA_kernel<<<NB4, 320, 0, stream>>>(0);
    gtB_kernel<false><<<gtB_blocks, 320, 0, stream>>>(b1, W2, 0);
    // layer 3
    gtA_kernel<<<NB4, 320, 0, stream>>>(1);
    gtB_kernel<false><<<gtB_blocks, 320, 0, stream>>>(b2, W3, 1);
    // final
    gtA_kernel<<<NB4, 320, 0, stream>>>(0);
    gtB_kernel<true><<<gtB_blocks, 320, 0, stream>>>(nullptr, nullptr, 0);
    // pool (+relu(+b3)) + linear
    pool_kernel<<<N_GRAPHS, 256, 0, stream>>>(b3, batch, eidx, Wl, bl, out);
}

// Round 16
// 147.375 us; speedup vs baseline: 1.3087x; 1.3087x over previous
//
#include <hip/hip_runtime.h>
#include <hip/hip_fp16.h>
#include <math.h>

#define N_NODES 100000
#define N_EDGES 1600000
#define N_FEATS 128
#define HIDDEN 20
#define N_GRAPHS 256

#define TILE 256
#define NB ((N_NODES + TILE - 1) / TILE)       // 391 buckets
#define SLOTS 5120                             // mean 4096 + 16 sigma slack
#define YSTRIDE 32                             // fp16 row padded to 64 B line

// Static device scratch (fully rewritten each call before any read).
// __device__ symbols resolved in DEVICE code only; host passes selectors.
__device__ __half g_yh[2][(size_t)N_NODES * YSTRIDE];  // fp16 tables, 2 x 6.4 MB
__device__ float  g_facc[(size_t)N_NODES * HIDDEN];    // final acc (f32), 8 MB
__device__ int    g_part[(size_t)NB * SLOTS];          // packed (src<<8)|dlocal
__device__ int    g_cursor[NB];
__device__ int    g_bbase[NB];
__device__ int    g_rowptr[N_NODES + 1];
__device__ int    g_col[N_EDGES];

// ---- inline index-dtype detection (int64 edge_index has zero odd words) -----
__device__ __forceinline__ int detect_is64(const int* __restrict__ e32) {
    int acc = 0;
    #pragma unroll
    for (int j = 0; j < 8; j++) {
        int k = j * (N_EDGES / 8) + 997 * j + 13;
        acc |= e32[2 * k + 1];
    }
    return acc == 0;
}

__device__ __forceinline__ void load_edge(const void* eidx, int is64, int e,
                                          int& s, int& d) {
    if (is64) {
        const long long* e64 = (const long long*)eidx;
        s = (int)e64[e];
        d = (int)e64[N_EDGES + e];
    } else {
        const int* e32 = (const int*)eidx;
        s = e32[e];
        d = e32[N_EDGES + e];
    }
}

__global__ __launch_bounds__(512) void zero_kernel() {
    const int i = threadIdx.x;
    if (i < NB) g_cursor[i] = 0;
}

// ---------------- partition: edges -> 256-node-tile buckets ------------------
__global__ __launch_bounds__(512) void part_kernel(const void* __restrict__ eidx) {
    __shared__ int hist[NB];
    __shared__ int base[NB];
    const int t = threadIdx.x;
    const int e0 = blockIdx.x * 4096;
    for (int i = t; i < NB; i += 512) hist[i] = 0;
    const int is64 = detect_is64((const int*)eidx);
    __syncthreads();

    int sc[8], dc[8];
    #pragma unroll
    for (int k = 0; k < 8; k++) {
        const int e = e0 + k * 512 + t;
        sc[k] = -1; dc[k] = 0;
        if (e < N_EDGES) {
            int s, d;
            load_edge(eidx, is64, e, s, d);
            if ((unsigned)s < N_NODES && (unsigned)d < N_NODES) {
                sc[k] = s; dc[k] = d;
                atomicAdd(&hist[d >> 8], 1);
            }
        }
    }
    __syncthreads();
    for (int b = t; b < NB; b += 512) {
        const int c = hist[b];
        base[b] = c ? atomicAdd(&g_cursor[b], c) : 0;
        hist[b] = 0;   // reuse as local rank counter
    }
    __syncthreads();
    #pragma unroll
    for (int k = 0; k < 8; k++) {
        if (sc[k] >= 0) {
            const int b = dc[k] >> 8;
            const int r = atomicAdd(&hist[b], 1);
            const int pos = base[b] + r;
            if (pos < SLOTS)
                g_part[(size_t)b * SLOTS + pos] = (sc[k] << 8) | (dc[k] & 255);
        }
    }
}

// ---------------- exclusive scan of bucket counts -> bases -------------------
__global__ __launch_bounds__(512) void scanbase_kernel() {
    __shared__ int lds[512];
    const int t = threadIdx.x;
    int v = (t < NB) ? min(g_cursor[t], SLOTS) : 0;
    lds[t] = v;
    __syncthreads();
    for (int off = 1; off < 512; off <<= 1) {
        int u = (t >= off) ? lds[t - off] : 0;
        __syncthreads();
        lds[t] += u;
        __syncthreads();
    }
    if (t < NB) g_bbase[t] = lds[t] - v;
    if (t == 511) g_rowptr[N_NODES] = lds[511];
}

// -------- per-bucket LDS counting sort -> CSR (rowptr + col) -----------------
__global__ __launch_bounds__(512) void bucketsort_kernel() {
    __shared__ int hist[TILE];
    __shared__ int pfx[TILE];
    __shared__ int cur[TILE];
    __shared__ int sorted[SLOTS];
    const int t = threadIdx.x;
    const int b = blockIdx.x;
    const int cnt = min(g_cursor[b], SLOTS);
    const int base = g_bbase[b];
    if (t < TILE) hist[t] = 0;
    __syncthreads();
    const int* __restrict__ part = g_part + (size_t)b * SLOTS;
    for (int i = t; i < cnt; i += 512) atomicAdd(&hist[part[i] & 255], 1);
    __syncthreads();
    if (t < TILE) pfx[t] = hist[t];
    __syncthreads();
    for (int off = 1; off < TILE; off <<= 1) {
        int u = (t < TILE && t >= off) ? pfx[t - off] : 0;
        __syncthreads();
        if (t < TILE) pfx[t] += u;
        __syncthreads();
    }
    if (t < TILE) {
        const int ex = pfx[t] - hist[t];   // exclusive prefix
        cur[t] = ex;
        const int node = b * TILE + t;
        if (node < N_NODES) g_rowptr[node] = base + ex;
    }
    __syncthreads();
    for (int i = t; i < cnt; i += 512) {
        const int rec = part[i];
        const int r = atomicAdd(&cur[rec & 255], 1);
        sorted[r] = rec >> 8;
    }
    __syncthreads();
    for (int i = t; i < cnt; i += 512) g_col[base + i] = sorted[i];
}

// ---------------- mm1: g_yh[0] = fp16(x @ W1) --------------------------------
// 4 threads per row (quarter-rows in registers), W k-interleaved in LDS
// (10 KB only -> high occupancy). Butterfly shfl combine within each quad.
__global__ __launch_bounds__(256) void mm1_kernel(const float* __restrict__ x,
                                                  const float* __restrict__ W) {  // 128x20
    __shared__ float ldsWp[N_FEATS * HIDDEN];   // permuted: [(jl*4+q)*20+c]
    const int t = threadIdx.x;
    for (int i = t; i < N_FEATS * HIDDEN; i += 256) {
        const int korig = i / HIDDEN;
        const int c = i - korig * HIDDEN;
        const int jl = korig & 31;
        const int q = korig >> 5;
        ldsWp[(jl * 4 + q) * HIDDEN + c] = W[i];
    }
    __syncthreads();
    const int r = t >> 2;
    const int q = t & 3;
    const int row = blockIdx.x * 64 + r;
    const bool valid = row < N_NODES;

    float4 v[8];
    if (valid) {
        const float4* rp = (const float4*)&x[(size_t)row * N_FEATS + q * 32];
        #pragma unroll
        for (int i = 0; i < 8; i++) v[i] = rp[i];   // 8 independent loads
    }
    float4 a0 = {0,0,0,0}, a1 = {0,0,0,0}, a2 = {0,0,0,0}, a3 = {0,0,0,0}, a4 = {0,0,0,0};
    if (valid) {
        #pragma unroll
        for (int i = 0; i < 8; i++) {
            const float xv[4] = {v[i].x, v[i].y, v[i].z, v[i].w};
            #pragma unroll
            for (int jj = 0; jj < 4; jj++) {
                const int jl = i * 4 + jj;
                const float4* wp = (const float4*)&ldsWp[(jl * 4 + q) * HIDDEN];
                const float xs = xv[jj];
                float4 w0 = wp[0], w1 = wp[1], w2 = wp[2], w3 = wp[3], w4 = wp[4];
                a0.x = fmaf(xs, w0.x, a0.x); a0.y = fmaf(xs, w0.y, a0.y);
                a0.z = fmaf(xs, w0.z, a0.z); a0.w = fmaf(xs, w0.w, a0.w);
                a1.x = fmaf(xs, w1.x, a1.x); a1.y = fmaf(xs, w1.y, a1.y);
                a1.z = fmaf(xs, w1.z, a1.z); a1.w = fmaf(xs, w1.w, a1.w);
                a2.x = fmaf(xs, w2.x, a2.x); a2.y = fmaf(xs, w2.y, a2.y);
                a2.z = fmaf(xs, w2.z, a2.z); a2.w = fmaf(xs, w2.w, a2.w);
                a3.x = fmaf(xs, w3.x, a3.x); a3.y = fmaf(xs, w3.y, a3.y);
                a3.z = fmaf(xs, w3.z, a3.z); a3.w = fmaf(xs, w3.w, a3.w);
                a4.x = fmaf(xs, w4.x, a4.x); a4.y = fmaf(xs, w4.y, a4.y);
                a4.z = fmaf(xs, w4.z, a4.z); a4.w = fmaf(xs, w4.w, a4.w);
            }
        }
    }
    // butterfly combine the 4 quarter sums within each quad (lanes r*4+q)
    float acc[20] = {a0.x, a0.y, a0.z, a0.w, a1.x, a1.y, a1.z, a1.w,
                     a2.x, a2.y, a2.z, a2.w, a3.x, a3.y, a3.z, a3.w,
                     a4.x, a4.y, a4.z, a4.w};
    #pragma unroll
    for (int off = 1; off <= 2; off <<= 1) {
        #pragma unroll
        for (int c = 0; c < 20; c++) acc[c] += __shfl_xor(acc[c], off);
    }
    if (valid) {
        __half* yp = &g_yh[0][(size_t)row * YSTRIDE];
        if (q == 0) {
            __half2 h0 = __float22half2_rn(make_float2(acc[0], acc[1]));
            __half2 h1 = __float22half2_rn(make_float2(acc[2], acc[3]));
            __half2 h2 = __float22half2_rn(make_float2(acc[4], acc[5]));
            __half2 h3 = __float22half2_rn(make_float2(acc[6], acc[7]));
            uint4 u; u.x = *(unsigned*)&h0; u.y = *(unsigned*)&h1;
            u.z = *(unsigned*)&h2; u.w = *(unsigned*)&h3;
            *(uint4*)&yp[0] = u;
        } else if (q == 1) {
            __half2 h0 = __float22half2_rn(make_float2(acc[8], acc[9]));
            __half2 h1 = __float22half2_rn(make_float2(acc[10], acc[11]));
            __half2 h2 = __float22half2_rn(make_float2(acc[12], acc[13]));
            __half2 h3 = __float22half2_rn(make_float2(acc[14], acc[15]));
            uint4 u; u.x = *(unsigned*)&h0; u.y = *(unsigned*)&h1;
            u.z = *(unsigned*)&h2; u.w = *(unsigned*)&h3;
            *(uint4*)&yp[8] = u;
        } else if (q == 2) {
            __half2 h0 = __float22half2_rn(make_float2(acc[16], acc[17]));
            __half2 h1 = __float22half2_rn(make_float2(acc[18], acc[19]));
            uint2 u; u.x = *(unsigned*)&h0; u.y = *(unsigned*)&h1;
            *(uint2*)&yp[16] = u;
        }
    }
}

// ----- fused gather+transform over fp16 table --------------------------------
// 320 threads = 64 nodes x 5 chunks (4 feats each). Row = one 64 B line.
// Gather loop unrolled x8 with batched independent loads (MLP for latency).
template<bool FINAL>
__global__ __launch_bounds__(320) void gt_kernel(const float* __restrict__ bias,
                                                 const float* __restrict__ W,  // 20x20
                                                 int src) {
    const __half* __restrict__ y = g_yh[src];
    __shared__ float hrow[64][HIDDEN + 1];
    __shared__ float ldsW[HIDDEN * HIDDEN];
    __shared__ float ldsB[HIDDEN];
    const int t = threadIdx.x;
    if (!FINAL) {
        for (int i = t; i < HIDDEN * HIDDEN; i += 320) ldsW[i] = W[i];
        if (t < HIDDEN) ldsB[t] = bias[t];
    }
    const int nl = t / 5;
    const int chunk = t - nl * 5;
    const int node = blockIdx.x * 64 + nl;
    float sx = 0.f, sy = 0.f, sz = 0.f, sw = 0.f;
    if (node < N_NODES) {
        const int beg = g_rowptr[node];
        const int end = g_rowptr[node + 1];
        const int cb = chunk * 4;
        int i = beg;
        for (; i + 8 <= end; i += 8) {
            // batch independent loads: 8 cols, then 8 rows in flight together
            int s[8];
            #pragma unroll
            for (int k = 0; k < 8; k++) s[k] = g_col[i + k];
            uint2 u[8];
            #pragma unroll
            for (int k = 0; k < 8; k++)
                u[k] = *(const uint2*)&y[(size_t)s[k] * YSTRIDE + cb];
            #pragma unroll
            for (int k = 0; k < 8; k++) {
                const float2 a = __half22float2(*(const __half2*)&u[k].x);
                const float2 b = __half22float2(*(const __half2*)&u[k].y);
                sx += a.x; sy += a.y; sz += b.x; sw += b.y;
            }
        }
        for (; i + 4 <= end; i += 4) {
            const int s0 = g_col[i + 0];
            const int s1 = g_col[i + 1];
            const int s2 = g_col[i + 2];
            const int s3 = g_col[i + 3];
            const uint2 u0 = *(const uint2*)&y[(size_t)s0 * YSTRIDE + cb];
            const uint2 u1 = *(const uint2*)&y[(size_t)s1 * YSTRIDE + cb];
            const uint2 u2 = *(const uint2*)&y[(size_t)s2 * YSTRIDE + cb];
            const uint2 u3 = *(const uint2*)&y[(size_t)s3 * YSTRIDE + cb];
            float2 a, b;
            a = __half22float2(*(const __half2*)&u0.x); b = __half22float2(*(const __half2*)&u0.y);
            sx += a.x; sy += a.y; sz += b.x; sw += b.y;
            a = __half22float2(*(const __half2*)&u1.x); b = __half22float2(*(const __half2*)&u1.y);
            sx += a.x; sy += a.y; sz += b.x; sw += b.y;
            a = __half22float2(*(const __half2*)&u2.x); b = __half22float2(*(const __half2*)&u2.y);
            sx += a.x; sy += a.y; sz += b.x; sw += b.y;
            a = __half22float2(*(const __half2*)&u3.x); b = __half22float2(*(const __half2*)&u3.y);
            sx += a.x; sy += a.y; sz += b.x; sw += b.y;
        }
        for (; i < end; i++) {
            const int s = g_col[i];
            const uint2 u = *(const uint2*)&y[(size_t)s * YSTRIDE + cb];
            const float2 f0 = __half22float2(*(const __half2*)&u.x);
            const float2 f1 = __half22float2(*(const __half2*)&u.y);
            sx += f0.x; sy += f0.y; sz += f1.x; sw += f1.y;
        }
        const uint2 u = *(const uint2*)&y[(size_t)node * YSTRIDE + cb];
        const float2 f0 = __half22float2(*(const __half2*)&u.x);
        const float2 f1 = __half22float2(*(const __half2*)&u.y);
        sx += f0.x; sy += f0.y; sz += f1.x; sw += f1.y;
    }
    if (FINAL) {
        if (node < N_NODES) {
            float4 o; o.x = sx; o.y = sy; o.z = sz; o.w = sw;
            *(float4*)&g_facc[(size_t)node * HIDDEN + chunk * 4] = o;
        }
        return;
    }
    if (node < N_NODES) {
        hrow[nl][chunk * 4 + 0] = sx;
        hrow[nl][chunk * 4 + 1] = sy;
        hrow[nl][chunk * 4 + 2] = sz;
        hrow[nl][chunk * 4 + 3] = sw;
    }
    __syncthreads();
    if (node < N_NODES) {
        float h[HIDDEN];
        #pragma unroll
        for (int c = 0; c < HIDDEN; c++) {
            float v = hrow[nl][c] + ldsB[c];
            h[c] = v > 0.f ? v : 0.f;
        }
        const int cb = chunk * 4;
        float s0 = 0.f, s1 = 0.f, s2 = 0.f, s3 = 0.f;
        #pragma unroll
        for (int k = 0; k < HIDDEN; k++) {
            const float* w = &ldsW[k * HIDDEN + cb];
            s0 = fmaf(h[k], w[0], s0);
            s1 = fmaf(h[k], w[1], s1);
            s2 = fmaf(h[k], w[2], s2);
            s3 = fmaf(h[k], w[3], s3);
        }
        __half2 o0 = __float22half2_rn(make_float2(s0, s1));
        __half2 o1 = __float22half2_rn(make_float2(s2, s3));
        uint2 u;
        u.x = *(unsigned*)&o0;
        u.y = *(unsigned*)&o1;
        *(uint2*)&g_yh[src ^ 1][(size_t)node * YSTRIDE + cb] = u;
    }
}

// ---------------- pool + final linear ----------------------------------------
__global__ __launch_bounds__(256) void pool_kernel(const float* __restrict__ b3,
                                                   const void* __restrict__ batch,
                                                   const void* __restrict__ eidx,
                                                   const float* __restrict__ Wl,  // 40x2
                                                   const float* __restrict__ bl,  // 2
                                                   float* __restrict__ out) {
    const float* __restrict__ acc3 = g_facc;
    const int g = blockIdx.x;
    const int t = threadIdx.x;
    const int is64 = detect_is64((const int*)eidx);
    const int* b32 = (const int*)batch;
    const long long* b64 = (const long long*)batch;
    #define BAT(i) (is64 ? (int)b64[i] : b32[i])
    int lo = 0, hi = N_NODES;
    while (lo < hi) { int mid = (lo + hi) >> 1; if (BAT(mid) < g) lo = mid + 1; else hi = mid; }
    const int start = lo;
    lo = start; hi = N_NODES;
    while (lo < hi) { int mid = (lo + hi) >> 1; if (BAT(mid) < g + 1) lo = mid + 1; else hi = mid; }
    const int end = lo;
    #undef BAT

    float b3r[HIDDEN];
    #pragma unroll
    for (int c = 0; c < HIDDEN; c++) b3r[c] = b3[c];
    float mx[HIDDEN], sm[HIDDEN];
    #pragma unroll
    for (int c = 0; c < HIDDEN; c++) { mx[c] = 0.f; sm[c] = 0.f; }  // relu >= 0

    for (int i = start + t; i < end; i += 256) {
        const float4* rp = (const float4*)&acc3[(size_t)i * HIDDEN];
        float4 q[5] = {rp[0], rp[1], rp[2], rp[3], rp[4]};
        const float* r = (const float*)q;
        #pragma unroll
        for (int c = 0; c < HIDDEN; c++) {
            float v = r[c] + b3r[c];
            v = v > 0.f ? v : 0.f;
            mx[c] = fmaxf(mx[c], v);
            sm[c] += v;
        }
    }
    #pragma unroll
    for (int off = 32; off >= 1; off >>= 1) {
        #pragma unroll
        for (int c = 0; c < HIDDEN; c++) {
            mx[c] = fmaxf(mx[c], __shfl_xor(mx[c], off));
            sm[c] += __shfl_xor(sm[c], off);
        }
    }
    __shared__ float smx[4][HIDDEN];
    __shared__ float ssm[4][HIDDEN];
    const int wave = t >> 6, lane = t & 63;
    if (lane == 0) {
        #pragma unroll
        for (int c = 0; c < HIDDEN; c++) { smx[wave][c] = mx[c]; ssm[wave][c] = sm[c]; }
    }
    __syncthreads();
    if (t == 0) {
        float cnt = (float)(end - start);
        float pooled[2 * HIDDEN];
        #pragma unroll
        for (int c = 0; c < HIDDEN; c++) {
            float m = smx[0][c], s = ssm[0][c];
            #pragma unroll
            for (int w = 1; w < 4; w++) { m = fmaxf(m, smx[w][c]); s += ssm[w][c]; }
            pooled[c] = m;
            pooled[HIDDEN + c] = s / fmaxf(cnt, 1.f);
        }
        #pragma unroll
        for (int c = 0; c < 2; c++) {
            float o = bl[c];
            #pragma unroll
            for (int k = 0; k < 2 * HIDDEN; k++) o = fmaf(pooled[k], Wl[k * 2 + c], o);
            out[g * 2 + c] = o;
        }
    }
}

extern "C" void kernel_launch(void* const* d_in, const int* in_sizes, int n_in,
                              void* d_out, int out_size, void* d_ws, size_t ws_size,
                              hipStream_t stream) {
    const float* x    = (const float*)d_in[0];
    const void* eidx  = d_in[1];
    const void* batch = d_in[2];
    const float* W1  = (const float*)d_in[3];
    const float* b1  = (const float*)d_in[4];
    const float* W2  = (const float*)d_in[5];
    const float* b2  = (const float*)d_in[6];
    const float* W3  = (const float*)d_in[7];
    const float* b3  = (const float*)d_in[8];
    const float* Wl  = (const float*)d_in[9];
    const float* bl  = (const float*)d_in[10];
    float* out = (float*)d_out;
    (void)d_ws; (void)ws_size;

    const int mm1_blocks = (N_NODES + 63) / 64;   // 1563
    const int gt_blocks  = (N_NODES + 63) / 64;   // 1563

    // CSR build via bucket partition + LDS counting sort (once, reused 3x)
    zero_kernel<<<1, 512, 0, stream>>>();
    part_kernel<<<NB, 512, 0, stream>>>(eidx);
    scanbase_kernel<<<1, 512, 0, stream>>>();
    bucketsort_kernel<<<NB, 512, 0, stream>>>();

    // layer 1: yh0 = fp16(x@W1)
    mm1_kernel<<<mm1_blocks, 256, 0, stream>>>(x, W1);
    // layer 2: yh1 = fp16(relu(yh0 + agg(yh0) + b1) @ W2)
    gt_kernel<false><<<gt_blocks, 320, 0, stream>>>(b1, W2, 0);
    // layer 3: yh0 = fp16(relu(yh1 + agg(yh1) + b2) @ W3)
    gt_kernel<false><<<gt_blocks, 320, 0, stream>>>(b2, W3, 1);
    // final: facc = f32(yh0 + agg(yh0))
    gt_kernel<true><<<gt_blocks, 320, 0, stream>>>(nullptr, nullptr, 0);
    // pool (+relu(+b3)) + linear
    pool_kernel<<<N_GRAPHS, 256, 0, stream>>>(b3, batch, eidx, Wl, bl, out);
}